// Round 12
// baseline (85.445 us; speedup 1.0000x reference)
//
#include <hip/hip_runtime.h>
#include <stdint.h>

// ---------------------------------------------------------------------------
// GSDepthRankingLoss on MI355X — R8 = R3-champion structure + bf16 table +
// 2-launch pipeline.
//   gs_prep : bitpack valid_mask + padded bf16 depth table + zero acc header
//   gs_main : PRNG -> in-block LDS compaction -> 7x7 bf16 crops with
//             COMPILER-scheduled loads (R7's asm vmcnt(0) batch removed: it
//             blocked load/sort interleave, -25us) -> pair loss -> block
//             reduce -> ticket finalize (threadfence reduction).
// JAX threefry (partitionable) verified bit-exact R0-R7.
// ---------------------------------------------------------------------------

#define IMG_W 1920
#define IMG_H 1080
#define N_PIX (IMG_W * IMG_H)
#define N_SAMP 518400          // int(1920*1080*0.25)
#define MAIN_BLKS 1013         // ceil(N_SAMP / 512)
#define PAD_VAL (-1000000.0f)
#define PW 968                 // padded table words per row (1936 px / 2)
#define PH 1088                // padded table rows
#define PAD16 0xC974u          // bf16(-1e6)

typedef unsigned long long ull;

struct Keys { uint32_t k[5][2][2]; };  // [randint id][k1|k2][key word]

// Threefry-2x32, 20 rounds (Random123 / JAX-compatible).
static __host__ __device__ inline void tf2x32(uint32_t k0, uint32_t k1,
                                              uint32_t x0, uint32_t x1,
                                              uint32_t& o0, uint32_t& o1)
{
  const uint32_t ks2 = k0 ^ k1 ^ 0x1BD11BDAu;
  x0 += k0; x1 += k1;
#define TFR(r) { x0 += x1; x1 = (x1 << (r)) | (x1 >> (32 - (r))); x1 ^= x0; }
  TFR(13) TFR(15) TFR(26) TFR(6)
  x0 += k1;  x1 += ks2 + 1u;
  TFR(17) TFR(29) TFR(16) TFR(24)
  x0 += ks2; x1 += k0 + 2u;
  TFR(13) TFR(15) TFR(26) TFR(6)
  x0 += k0;  x1 += k1 + 3u;
  TFR(17) TFR(29) TFR(16) TFR(24)
  x0 += k1;  x1 += ks2 + 4u;
  TFR(13) TFR(15) TFR(26) TFR(6)
  x0 += ks2; x1 += k0 + 5u;
#undef TFR
  o0 = x0; o1 = x1;
}

__device__ __forceinline__ uint32_t jrbits(const uint32_t kk[2], uint32_t f)
{
  uint32_t a, b;
  tf2x32(kk[0], kk[1], 0u, f, a, b);   // partitionable: counts = (0, f)
  return a ^ b;                        // 32-bit fold
}

__device__ __forceinline__ uint32_t jrandint(const Keys& K, int r, uint32_t f,
                                             uint32_t span)
{
  const uint32_t hi = jrbits(K.k[r][0], f);
  const uint32_t lo = jrbits(K.k[r][1], f);
  uint32_t m = 65536u % span;
  m = (m * m) % span;
  return ((hi % span) * m + (lo % span)) % span;
}

static void compute_keys(Keys& K)
{
  uint32_t ks[5][2];
  for (uint32_t t = 0; t < 5; t++) {
    uint32_t a, b; tf2x32(0u, 42u, 0u, t, a, b);   // split of key(42)
    ks[t][0] = a; ks[t][1] = b;
  }
  for (int r = 0; r < 5; r++) {                    // randint's internal _split
    uint32_t a, b;
    tf2x32(ks[r][0], ks[r][1], 0u, 0u, a, b); K.k[r][0][0] = a; K.k[r][0][1] = b;
    tf2x32(ks[r][0], ks[r][1], 0u, 1u, a, b); K.k[r][1][0] = a; K.k[r][1][1] = b;
  }
}

__device__ __forceinline__ bool bittest(const ull* __restrict__ vb, uint32_t idx)
{
  return ((vb[idx >> 6] >> (idx & 63u)) & 1ull) != 0ull;
}

// ---------------- K1: prep = bitpack + padded bf16 table + zero header ------
__global__ __launch_bounds__(256) void gs_prep(
    const int*   __restrict__ vmask,
    const float* __restrict__ tgt,
    ull*      __restrict__ vbits,
    uint32_t* __restrict__ t16p,
    uint32_t* __restrict__ hdr)      // [rank, cont, cnt, done]
{
  const uint32_t gid = blockIdx.x * 256u + threadIdx.x;  // 8100*256 == N_PIX
  const ull ball = __ballot(vmask[gid] != 0);
  if ((threadIdx.x & 63u) == 0) vbits[gid >> 6] = ball;

  if (gid < (uint32_t)(PW * PH)) {
    const uint32_t wy = gid / PW, wx = gid % PW;
    const int sy  = (int)wy - 4;
    const int sx0 = 2 * (int)wx - 4;
    uint32_t lo = PAD16, hi = PAD16;
    if (sy >= 0 && sy < IMG_H) {
      const uint32_t* src = (const uint32_t*)tgt + (size_t)sy * IMG_W;
      if (sx0     >= 0 && sx0     < IMG_W) lo = src[sx0] >> 16;
      if (sx0 + 1 >= 0 && sx0 + 1 < IMG_W) hi = src[sx0 + 1] >> 16;
    }
    t16p[gid] = lo | (hi << 16);
  }
  if (gid < 4) hdr[gid] = 0;
}

// nbr-th nearest neighbour from the PADDED bf16 table. Plain memcpy row
// loads (one dwordx4 each) — compiler interleaves loads with sort work and
// inserts fine-grained waits (this beat the asm vmcnt(0) batch by ~25us).
// Returns neighbour flat index; center (bf16) depth via sd_out.
__device__ __forceinline__ int crop_neighbor16(
    const uint32_t* __restrict__ t16p, int sy, int sx,
    float& sd_out, uint32_t nbr)
{
  const int prow0 = sy + 1;              // (sy-3) + 4 pad
  const int pcol  = sx + 1;              // (sx-3) + 4 pad
  const int ex    = pcol & ~1;           // even px base
  const uint32_t s = (uint32_t)(pcol & 1);
  const uint32_t* p = t16p + (size_t)prow0 * PW + (ex >> 1);

  uint32_t R[7][4];
#pragma unroll
  for (int r = 0; r < 7; r++)
    __builtin_memcpy(&R[r][0], p + (size_t)r * PW, 16);   // 1x dwordx4

  // center = crop (row 3, col 3) -> halfword s+3 of row 3
  const uint32_t sdbits = s ? (R[3][2] << 16) : (R[3][1] & 0xFFFF0000u);
  const float sd = __uint_as_float(sdbits);
  sd_out = sd;

  // 15 smallest of 49 keys: (|v-sd|bits & ~63) | pos; stable ties by pos.
  uint32_t arr[15];
#pragma unroll
  for (int t = 0; t < 15; t++) arr[t] = 0xFFFFFFFFu;

#pragma unroll
  for (int r = 0; r < 7; r++) {
#pragma unroll
    for (int c = 0; c < 7; c++) {
      uint32_t bits;
      if (c & 1) bits = s ? (R[r][(c + 1) >> 1] << 16)
                          : (R[r][c >> 1] & 0xFFFF0000u);
      else       bits = s ? (R[r][c >> 1] & 0xFFFF0000u)
                          : (R[r][c >> 1] << 16);
      const float v = __uint_as_float(bits);
      const int q = r * 7 + c;
      uint32_t key = (__float_as_uint(v - sd) & 0x7FFFFFC0u) | (uint32_t)q;
      const int depth = (q + 1 < 15) ? (q + 1) : 15;     // triangular insert
#pragma unroll
      for (int t = 0; t < 15; t++) {
        if (t < depth) {
          const uint32_t lo = min(key, arr[t]);
          const uint32_t hi = max(key, arr[t]);
          arr[t] = lo; key = hi;
        }
      }
    }
  }

  uint32_t relkey = 0;
#pragma unroll
  for (int t = 1; t < 15; t++)
    if ((uint32_t)t == nbr) relkey = arr[t];
  const uint32_t rel = relkey & 63u;
  return (sy - 3 + (int)(rel / 7u)) * IMG_W + (sx - 3 + (int)(rel % 7u));
}

// ---------------- K2: fused main (512 samples/block) + ticket finalize ------
// ent (64b): [ui:20 @44][sy0:11 @33][sx0:11 @22][sy1:11 @11][sx1:11 @0]
__global__ __launch_bounds__(256, 2) void gs_main(
    const uint32_t* __restrict__ t16p,
    const float* __restrict__ rnd,
    const ull*   __restrict__ vbits,
    float* __restrict__ acc,         // hdr: [rank, cont, cnt][done]
    float* __restrict__ out,
    Keys K)
{
  __shared__ ull      ent[512];
  __shared__ float    res_sd[1024];
  __shared__ int      res_ni[1024];
  __shared__ uint32_t scnt[8];
  __shared__ float    partial[12];

  const uint32_t tid  = threadIdx.x;
  const uint32_t lane = tid & 63u;
  const uint32_t wave = tid >> 6;

  // ------- phase A: PRNG + sample mask, 2 samples/thread, LDS compaction ----
  ull eb[2];
  bool ok[2];
#pragma unroll
  for (int h = 0; h < 2; h++) {
    const uint32_t ui = blockIdx.x * 512u + (uint32_t)h * 256u + tid;
    bool o = false;
    ull ee = 0;
    if (ui < N_SAMP) {
      const uint32_t syb = jrandint(K, 0, ui, 840u);    // H - 240
      const uint32_t sxb = jrandint(K, 1, ui, 1680u);   // W - 240
      const uint32_t oy0 = jrandint(K, 2, 2u * ui,      240u);
      const uint32_t oy1 = jrandint(K, 2, 2u * ui + 1u, 240u);
      const uint32_t ox0 = jrandint(K, 3, 2u * ui,      240u);
      const uint32_t ox1 = jrandint(K, 3, 2u * ui + 1u, 240u);
      const uint32_t sy0 = syb + oy0, sy1 = syb + oy1;
      const uint32_t sx0 = sxb + ox0, sx1 = sxb + ox1;
      o = bittest(vbits, sy0 * IMG_W + sx0) &&
          bittest(vbits, sy1 * IMG_W + sx1);
      ee = ((ull)ui << 44) |
           ((ull)sy0 << 33) | ((ull)sx0 << 22) |
           ((ull)sy1 << 11) |  (ull)sx1;
    }
    ok[h] = o; eb[h] = ee;
  }

  const ull b0 = __ballot(ok[0]);
  const ull b1 = __ballot(ok[1]);
  if (lane == 0) {
    scnt[wave]     = (uint32_t)__popcll(b0);
    scnt[4 + wave] = (uint32_t)__popcll(b1);
  }
  __syncthreads();

  uint32_t base0 = 0, sum0 = 0, base1 = 0, nsurv = 0;
#pragma unroll
  for (uint32_t w = 0; w < 4; w++) {
    if (w < wave) { base0 += scnt[w]; base1 += scnt[4 + w]; }
    sum0  += scnt[w];
    nsurv += scnt[w] + scnt[4 + w];
  }
  base1 += sum0;

  if (ok[0]) ent[base0 + (uint32_t)__popcll(b0 & ((1ull << lane) - 1ull))] = eb[0];
  if (ok[1]) ent[base1 + (uint32_t)__popcll(b1 & ((1ull << lane) - 1ull))] = eb[1];
  __syncthreads();

  // ------- phase B: one 7x7 crop per thread (dense, ~2*nsurv ~= 256) --------
  for (uint32_t t = tid; t < 2u * nsurv; t += 256u) {
    const ull ee = ent[t >> 1];
    const int jj = (int)(t & 1u);
    const uint32_t eui = (uint32_t)(ee >> 44);
    const int sy = jj ? (int)((ee >> 11) & 2047u) : (int)((ee >> 33) & 2047u);
    const int sx = jj ? (int)( ee        & 2047u) : (int)((ee >> 22) & 2047u);
    const uint32_t nbr = 1u + jrandint(K, 4, 2u * eui + (uint32_t)jj, 14u);
    float sd;
    const int nidx = crop_neighbor16(t16p, sy, sx, sd, nbr);
    res_sd[t] = sd;
    res_ni[t] = bittest(vbits, (uint32_t)nidx) ? nidx : -1;
  }
  __syncthreads();

  // ------- phase C: pair combine + loss --------------------------------------
  float rank_c = 0.f, cont_c = 0.f, cnt_c = 0.f;
  for (uint32_t sI = tid; sI < nsurv; sI += 256u) {
    const int n0 = res_ni[2u * sI], n1 = res_ni[2u * sI + 1u];
    if ((n0 >= 0) && (n1 >= 0)) {
      const ull ee = ent[sI];
      const int esy0 = (int)((ee >> 33) & 2047u), esx0 = (int)((ee >> 22) & 2047u);
      const int esy1 = (int)((ee >> 11) & 2047u), esx1 = (int)( ee        & 2047u);
      const float r0 = rnd[esy0 * IMG_W + esx0];
      const float r1 = rnd[esy1 * IMG_W + esx1];
      const float q0 = rnd[n0], q1 = rnd[n1];
      const float sd0 = res_sd[2u * sI], sd1 = res_sd[2u * sI + 1u];
      const bool keep = sd0 >= sd1;            // stable argsort(-depth)
      const float ra = keep ? r0 : r1;
      const float rb = keep ? r1 : r0;
      rank_c += fmaxf(ra - rb + 1e-4f, 0.f);
      cont_c += fmaxf(fabsf(r0 - q0) - 1e-4f, 0.f)
              + fmaxf(fabsf(r1 - q1) - 1e-4f, 0.f);
      cnt_c  += 1.f;
    }
  }

  // ------- block reduce -> 3 atomics -> ticket; last block finalizes --------
#pragma unroll
  for (int off = 32; off > 0; off >>= 1) {
    rank_c += __shfl_down(rank_c, off);
    cont_c += __shfl_down(cont_c, off);
    cnt_c  += __shfl_down(cnt_c, off);
  }
  if (lane == 0) {
    partial[wave * 3 + 0] = rank_c;
    partial[wave * 3 + 1] = cont_c;
    partial[wave * 3 + 2] = cnt_c;
  }
  __syncthreads();
  if (tid == 0) {
    const float s0 = partial[0] + partial[3] + partial[6] + partial[9];
    const float s1 = partial[1] + partial[4] + partial[7] + partial[10];
    const float s2 = partial[2] + partial[5] + partial[8] + partial[11];
    atomicAdd(acc + 0, s0);
    atomicAdd(acc + 1, s1);
    atomicAdd(acc + 2, s2);
    __threadfence();
    uint32_t* done = (uint32_t*)acc + 3;
    const uint32_t old = atomicAdd(done, 1u);
    if (old == (uint32_t)gridDim.x - 1u) {     // last block: finalize
      __threadfence();
      const float a0 = atomicAdd(acc + 0, 0.f);  // coherent reads
      const float a1 = atomicAdd(acc + 1, 0.f);
      const float a2 = atomicAdd(acc + 2, 0.f);
      const float denom = fmaxf(a2, 1.0f);
      out[0] = 0.2f  * (a0 / denom);             // WEIGHT * rank_mean
      out[1] = 0.02f * (a1 / (denom * 2.0f));    // WEIGHT*CONT_W * cont_mean
    }
  }
}

// ---------------- fallback (ws too small): fp32 fused, raw vmask ------------
__device__ __forceinline__ int crop_neighbor32(const float* __restrict__ tgt,
                                               int sy, int sx, float sd,
                                               uint32_t nbr)
{
  float v[7][8];
  const bool interior = (sy >= 3) && (sy <= IMG_H - 4) &&
                        (sx >= 3) && (sx <= IMG_W - 5);
  if (interior) {
    const float* p = tgt + (sy - 3) * IMG_W + (sx - 3);
#pragma unroll
    for (int r = 0; r < 7; r++)
      __builtin_memcpy(&v[r][0], p + r * IMG_W, 32);
  } else {
#pragma unroll
    for (int r = 0; r < 7; r++) {
      const int yy = sy - 3 + r;
      const bool rok = (yy >= 0) && (yy < IMG_H);
#pragma unroll
      for (int c = 0; c < 8; c++) {
        const int xx = sx - 3 + c;
        const bool okc = rok && (c < 7) && (xx >= 0) && (xx < IMG_W);
        v[r][c] = okc ? tgt[yy * IMG_W + xx] : PAD_VAL;
      }
    }
  }
  uint32_t arr[15];
#pragma unroll
  for (int t = 0; t < 15; t++) arr[t] = 0xFFFFFFFFu;
#pragma unroll
  for (int r = 0; r < 7; r++) {
#pragma unroll
    for (int c = 0; c < 7; c++) {
      const int q = r * 7 + c;
      uint32_t key = (__float_as_uint(v[r][c] - sd) & 0x7FFFFFC0u) | (uint32_t)q;
      const int depth = (q + 1 < 15) ? (q + 1) : 15;
#pragma unroll
      for (int t = 0; t < 15; t++) {
        if (t < depth) {
          const uint32_t lo = min(key, arr[t]);
          const uint32_t hi = max(key, arr[t]);
          arr[t] = lo; key = hi;
        }
      }
    }
  }
  uint32_t relkey = 0;
#pragma unroll
  for (int t = 1; t < 15; t++)
    if ((uint32_t)t == nbr) relkey = arr[t];
  const uint32_t rel = relkey & 63u;
  return (sy - 3 + (int)(rel / 7u)) * IMG_W + (sx - 3 + (int)(rel % 7u));
}

__global__ __launch_bounds__(256, 2) void gs_fused(
    const float* __restrict__ tgt,
    const float* __restrict__ rnd,
    const int*   __restrict__ vmask,
    float* __restrict__ acc,
    Keys K)
{
  __shared__ float partial[12];
  const uint32_t tid  = threadIdx.x;
  const uint32_t lane = tid & 63u;
  const uint32_t wave = tid >> 6;
  const uint32_t ui   = blockIdx.x * 256u + tid;

  float rank_c = 0.f, cont_c = 0.f, cnt_c = 0.f;
  if (ui < N_SAMP) {
    const uint32_t syb = jrandint(K, 0, ui, 840u);
    const uint32_t sxb = jrandint(K, 1, ui, 1680u);
    int sy[2], sx[2], sidx[2];
    float sd[2];
    bool sm = true;
#pragma unroll
    for (int j = 0; j < 2; j++) {
      sy[j] = (int)(syb + jrandint(K, 2, 2u * ui + (uint32_t)j, 240u));
      sx[j] = (int)(sxb + jrandint(K, 3, 2u * ui + (uint32_t)j, 240u));
      sidx[j] = sy[j] * IMG_W + sx[j];
      sd[j] = tgt[sidx[j]];
      sm = sm && (vmask[sidx[j]] != 0);
    }
    if (sm) {
      int nidx[2]; bool nm = true;
#pragma unroll
      for (int j = 0; j < 2; j++) {
        const uint32_t nbr = 1u + jrandint(K, 4, 2u * ui + (uint32_t)j, 14u);
        nidx[j] = crop_neighbor32(tgt, sy[j], sx[j], sd[j], nbr);
        nm = nm && (vmask[nidx[j]] != 0);
      }
      if (nm) {
        const float r0 = rnd[sidx[0]], r1 = rnd[sidx[1]];
        const float q0 = rnd[nidx[0]], q1 = rnd[nidx[1]];
        const bool keep = sd[0] >= sd[1];
        const float ra = keep ? r0 : r1;
        const float rb = keep ? r1 : r0;
        rank_c = fmaxf(ra - rb + 1e-4f, 0.f);
        cont_c = fmaxf(fabsf(r0 - q0) - 1e-4f, 0.f)
               + fmaxf(fabsf(r1 - q1) - 1e-4f, 0.f);
        cnt_c = 1.f;
      }
    }
  }
#pragma unroll
  for (int off = 32; off > 0; off >>= 1) {
    rank_c += __shfl_down(rank_c, off);
    cont_c += __shfl_down(cont_c, off);
    cnt_c  += __shfl_down(cnt_c, off);
  }
  if (lane == 0) {
    partial[wave * 3 + 0] = rank_c;
    partial[wave * 3 + 1] = cont_c;
    partial[wave * 3 + 2] = cnt_c;
  }
  __syncthreads();
  if (tid < 3) {
    const float sm2 = partial[tid] + partial[3 + tid] +
                      partial[6 + tid] + partial[9 + tid];
    atomicAdd(acc + tid, sm2);
  }
}

__global__ void gs_finalize(const float* __restrict__ acc, float* __restrict__ out)
{
  const float denom = fmaxf(acc[2], 1.0f);
  out[0] = 0.2f  * (acc[0] / denom);
  out[1] = 0.02f * (acc[1] / (denom * 2.0f));
}

extern "C" void kernel_launch(void* const* d_in, const int* in_sizes, int n_in,
                              void* d_out, int out_size, void* d_ws, size_t ws_size,
                              hipStream_t stream)
{
  (void)in_sizes; (void)n_in; (void)out_size;
  const float* tgt   = (const float*)d_in[0];
  const float* rnd   = (const float*)d_in[1];
  const int*   vmask = (const int*)d_in[2];
  float* out = (float*)d_out;

  // ws layout (16B-aligned):
  //   [0,16)     hdr: acc[3 floats] + done[u32]   (zeroed by gs_prep)
  //   +259200    vbits bit table
  //   +4213504   t16p padded bf16 table (968w x 1088r x 4B)
  char* p = (char*)d_ws;
  float*    acc   = (float*)p;
  ull*      vbits = (ull*)(p + 16);
  uint32_t* t16p  = (uint32_t*)(p + 16 + 259200);
  const size_t need = 16 + 259200 + 4213504;

  Keys K;
  compute_keys(K);

  if (ws_size >= need) {
    gs_prep<<<N_PIX / 256, 256, 0, stream>>>(vmask, tgt, vbits, t16p,
                                             (uint32_t*)acc);
    gs_main<<<MAIN_BLKS, 256, 0, stream>>>(t16p, rnd, vbits, acc, out, K);
  } else {
    hipMemsetAsync(acc, 0, 16, stream);
    gs_fused<<<N_SAMP / 256, 256, 0, stream>>>(tgt, rnd, vmask, acc, K);
    gs_finalize<<<1, 1, 0, stream>>>(acc, out);
  }
}

// Round 13
// 65.674 us; speedup vs baseline: 1.3010x; 1.3010x over previous
//
#include <hip/hip_runtime.h>
#include <stdint.h>

// ---------------------------------------------------------------------------
// GSDepthRankingLoss on MI355X — R13 = R3-round4 champion (fp32 crops, bitpack,
// 60.4us, absmax 0) + ONE change: 1024 samples/block, phase B processes crop
// PAIRS with interleaved insertion networks (2 independent dep chains per
// thread) to attack the measured latency-stall bound (VALUBusy ~35%, ~8x
// above the 11us issue floor) via per-wave ILP instead of occupancy.
// JAX threefry (partitionable) verified bit-exact R0-R12.
// ---------------------------------------------------------------------------

#define IMG_W 1920
#define IMG_H 1080
#define N_PIX (IMG_W * IMG_H)
#define N_SAMP 518400          // int(1920*1080*0.25)
#define MAIN_BLKS 507          // ceil(N_SAMP / 1024)
#define PAD_VAL (-1000000.0f)

typedef unsigned long long ull;

struct Keys { uint32_t k[5][2][2]; };  // [randint id][k1|k2][key word]

// Threefry-2x32, 20 rounds (Random123 / JAX-compatible).
static __host__ __device__ inline void tf2x32(uint32_t k0, uint32_t k1,
                                              uint32_t x0, uint32_t x1,
                                              uint32_t& o0, uint32_t& o1)
{
  const uint32_t ks2 = k0 ^ k1 ^ 0x1BD11BDAu;
  x0 += k0; x1 += k1;
#define TFR(r) { x0 += x1; x1 = (x1 << (r)) | (x1 >> (32 - (r))); x1 ^= x0; }
  TFR(13) TFR(15) TFR(26) TFR(6)
  x0 += k1;  x1 += ks2 + 1u;
  TFR(17) TFR(29) TFR(16) TFR(24)
  x0 += ks2; x1 += k0 + 2u;
  TFR(13) TFR(15) TFR(26) TFR(6)
  x0 += k0;  x1 += k1 + 3u;
  TFR(17) TFR(29) TFR(16) TFR(24)
  x0 += k1;  x1 += ks2 + 4u;
  TFR(13) TFR(15) TFR(26) TFR(6)
  x0 += ks2; x1 += k0 + 5u;
#undef TFR
  o0 = x0; o1 = x1;
}

__device__ __forceinline__ uint32_t jrbits(const uint32_t kk[2], uint32_t f)
{
  uint32_t a, b;
  tf2x32(kk[0], kk[1], 0u, f, a, b);   // partitionable: counts = (0, f)
  return a ^ b;                        // 32-bit fold
}

__device__ __forceinline__ uint32_t jrandint(const Keys& K, int r, uint32_t f,
                                             uint32_t span)
{
  const uint32_t hi = jrbits(K.k[r][0], f);
  const uint32_t lo = jrbits(K.k[r][1], f);
  uint32_t m = 65536u % span;
  m = (m * m) % span;
  return ((hi % span) * m + (lo % span)) % span;
}

static void compute_keys(Keys& K)
{
  uint32_t ks[5][2];
  for (uint32_t t = 0; t < 5; t++) {
    uint32_t a, b; tf2x32(0u, 42u, 0u, t, a, b);   // split of key(42)
    ks[t][0] = a; ks[t][1] = b;
  }
  for (int r = 0; r < 5; r++) {                    // randint's internal _split
    uint32_t a, b;
    tf2x32(ks[r][0], ks[r][1], 0u, 0u, a, b); K.k[r][0][0] = a; K.k[r][0][1] = b;
    tf2x32(ks[r][0], ks[r][1], 0u, 1u, a, b); K.k[r][1][0] = a; K.k[r][1][1] = b;
  }
}

// valid test: bit table if available (L2-resident), else raw int mask
__device__ __forceinline__ bool validat(const ull* __restrict__ vb,
                                        const int* __restrict__ vm, uint32_t idx)
{
  if (vb) return ((vb[idx >> 6] >> (idx & 63u)) & 1ull) != 0ull;
  return vm[idx] != 0;
}

// ---------------- K1: bitpack valid mask (2073600 ints -> 259KB) ------------
__global__ __launch_bounds__(256) void gs_bitpack(
    const int* __restrict__ vmask,
    ull* __restrict__ vbits)
{
  const uint32_t gid = blockIdx.x * 256u + threadIdx.x;   // 8100*256 == N_PIX
  const ull ball = __ballot(vmask[gid] != 0);
  if ((threadIdx.x & 63u) == 0) vbits[gid >> 6] = ball;
}

// TWO crops, interleaved: rows of both loaded, then a fused sort loop whose
// inner k-unroll alternates the two 15-slot insertion networks so one chain's
// dependency stalls are covered by the other's independent ops.
__device__ __forceinline__ void crop_pair(
    const float* __restrict__ tgt,
    const int* sy, const int* sx, const float* sd,
    const uint32_t* nbr, int* nidx)
{
  float v[2][7][8];
#pragma unroll
  for (int k = 0; k < 2; k++) {
    const bool interior = (sy[k] >= 3) && (sy[k] <= IMG_H - 4) &&
                          (sx[k] >= 3) && (sx[k] <= IMG_W - 5);
    if (interior) {
      const float* p = tgt + (sy[k] - 3) * IMG_W + (sx[k] - 3);
#pragma unroll
      for (int r = 0; r < 7; r++)
        __builtin_memcpy(&v[k][r][0], p + r * IMG_W, 32);   // 2x dwordx4
    } else {
      // rare edge path (~1e-4): guarded scalar loads, PAD semantics
#pragma unroll
      for (int r = 0; r < 7; r++) {
        const int yy = sy[k] - 3 + r;
        const bool rok = (yy >= 0) && (yy < IMG_H);
#pragma unroll
        for (int c = 0; c < 8; c++) {
          const int xx = sx[k] - 3 + c;
          const bool okc = rok && (c < 7) && (xx >= 0) && (xx < IMG_W);
          v[k][r][c] = okc ? tgt[yy * IMG_W + xx] : PAD_VAL;
        }
      }
    }
  }

  // 15 smallest of 49 keys per crop: (|v-sd|bits & ~63) | pos; stable ties.
  uint32_t arr[2][15];
#pragma unroll
  for (int k = 0; k < 2; k++)
#pragma unroll
    for (int t = 0; t < 15; t++) arr[k][t] = 0xFFFFFFFFu;

#pragma unroll
  for (int r = 0; r < 7; r++) {
#pragma unroll
    for (int c = 0; c < 7; c++) {
      const int q = r * 7 + c;
      const int depth = (q + 1 < 15) ? (q + 1) : 15;   // triangular insert
#pragma unroll
      for (int k = 0; k < 2; k++) {                     // interleave chains
        uint32_t key = (__float_as_uint(v[k][r][c] - sd[k]) & 0x7FFFFFC0u)
                     | (uint32_t)q;
#pragma unroll
        for (int t = 0; t < 15; t++) {
          if (t < depth) {
            const uint32_t lo = min(key, arr[k][t]);
            const uint32_t hi = max(key, arr[k][t]);
            arr[k][t] = lo; key = hi;
          }
        }
      }
    }
  }

#pragma unroll
  for (int k = 0; k < 2; k++) {
    uint32_t relkey = 0;
#pragma unroll
    for (int t = 1; t < 15; t++)
      if ((uint32_t)t == nbr[k]) relkey = arr[k][t];
    const uint32_t rel = relkey & 63u;
    nidx[k] = (sy[k] - 3 + (int)(rel / 7u)) * IMG_W
            + (sx[k] - 3 + (int)(rel % 7u));
  }
}

// ---------------- K2: fused main, 1024 samples/block ------------------------
// ent (64b): [ui:20 @44][sy0:11 @33][sx0:11 @22][sy1:11 @11][sx1:11 @0]
__global__ __launch_bounds__(256, 2) void gs_fused(
    const float* __restrict__ tgt,
    const float* __restrict__ rnd,
    const int*   __restrict__ vmask,
    const ull*   __restrict__ vbits,   // may be nullptr
    float* __restrict__ acc,
    Keys K)
{
  __shared__ ull      ent[1024];
  __shared__ float    res_sd[2048];
  __shared__ int      res_ni[2048];
  __shared__ uint32_t scnt[16];        // [h][wave]
  __shared__ float    partial[12];

  const uint32_t tid  = threadIdx.x;
  const uint32_t lane = tid & 63u;
  const uint32_t wave = tid >> 6;

  // ------- phase A: PRNG + sample mask, 4 samples/thread, LDS compaction ----
  ull  eb[4];
  ull  bal[4];
  bool ok[4];
#pragma unroll
  for (int h = 0; h < 4; h++) {
    const uint32_t ui = blockIdx.x * 1024u + (uint32_t)h * 256u + tid;
    bool o = false;
    ull ee = 0;
    if (ui < N_SAMP) {
      const uint32_t syb = jrandint(K, 0, ui, 840u);    // H - 240
      const uint32_t sxb = jrandint(K, 1, ui, 1680u);   // W - 240
      const uint32_t oy0 = jrandint(K, 2, 2u * ui,      240u);
      const uint32_t oy1 = jrandint(K, 2, 2u * ui + 1u, 240u);
      const uint32_t ox0 = jrandint(K, 3, 2u * ui,      240u);
      const uint32_t ox1 = jrandint(K, 3, 2u * ui + 1u, 240u);
      const uint32_t sy0 = syb + oy0, sy1 = syb + oy1;
      const uint32_t sx0 = sxb + ox0, sx1 = sxb + ox1;
      o = validat(vbits, vmask, sy0 * IMG_W + sx0) &&
          validat(vbits, vmask, sy1 * IMG_W + sx1);
      ee = ((ull)ui << 44) |
           ((ull)sy0 << 33) | ((ull)sx0 << 22) |
           ((ull)sy1 << 11) |  (ull)sx1;
    }
    ok[h] = o; eb[h] = ee;
    bal[h] = __ballot(o);
    if (lane == 0) scnt[(uint32_t)h * 4u + wave] = (uint32_t)__popcll(bal[h]);
  }
  __syncthreads();

  uint32_t run = 0, baseh[4];
#pragma unroll
  for (uint32_t h = 0; h < 4; h++) {
    uint32_t b = run;
#pragma unroll
    for (uint32_t w = 0; w < 4; w++) {
      const uint32_t cwh = scnt[h * 4u + w];
      if (w < wave) b += cwh;
      run += cwh;
    }
    baseh[h] = b;
  }
  const uint32_t nsurv = run;

#pragma unroll
  for (int h = 0; h < 4; h++)
    if (ok[h])
      ent[baseh[h] + (uint32_t)__popcll(bal[h] & ((1ull << lane) - 1ull))] = eb[h];
  __syncthreads();

  // ------- phase B: crop PAIRS (2 per thread), interleaved dep chains -------
  const uint32_t m = 2u * nsurv;                 // crops (~512)
  for (uint32_t t0 = tid; t0 < m; t0 += 512u) {
    const uint32_t tA = t0;
    const uint32_t tB = t0 + 256u;
    const bool hasB = (tB < m);
    const uint32_t tt[2] = { tA, hasB ? tB : tA };

    int sy[2], sx[2], nidx[2];
    uint32_t nbr[2];
    float sd[2];
#pragma unroll
    for (int k = 0; k < 2; k++) {
      const ull ee = ent[tt[k] >> 1];
      const int jj = (int)(tt[k] & 1u);
      const uint32_t eui = (uint32_t)(ee >> 44);
      sy[k] = jj ? (int)((ee >> 11) & 2047u) : (int)((ee >> 33) & 2047u);
      sx[k] = jj ? (int)( ee        & 2047u) : (int)((ee >> 22) & 2047u);
      nbr[k] = 1u + jrandint(K, 4, 2u * eui + (uint32_t)jj, 14u);
      sd[k] = tgt[sy[k] * IMG_W + sx[k]];
    }

    crop_pair(tgt, sy, sx, sd, nbr, nidx);

    res_sd[tA] = sd[0];
    res_ni[tA] = validat(vbits, vmask, (uint32_t)nidx[0]) ? nidx[0] : -1;
    if (hasB) {
      res_sd[tB] = sd[1];
      res_ni[tB] = validat(vbits, vmask, (uint32_t)nidx[1]) ? nidx[1] : -1;
    }
  }
  __syncthreads();

  // ------- phase C: pair combine + loss --------------------------------------
  float rank_c = 0.f, cont_c = 0.f, cnt_c = 0.f;
  for (uint32_t sI = tid; sI < nsurv; sI += 256u) {
    const int n0 = res_ni[2u * sI], n1 = res_ni[2u * sI + 1u];
    if ((n0 >= 0) && (n1 >= 0)) {
      const ull ee = ent[sI];
      const int esy0 = (int)((ee >> 33) & 2047u), esx0 = (int)((ee >> 22) & 2047u);
      const int esy1 = (int)((ee >> 11) & 2047u), esx1 = (int)( ee        & 2047u);
      const float r0 = rnd[esy0 * IMG_W + esx0];
      const float r1 = rnd[esy1 * IMG_W + esx1];
      const float q0 = rnd[n0], q1 = rnd[n1];
      const float sd0 = res_sd[2u * sI], sd1 = res_sd[2u * sI + 1u];
      const bool keep = sd0 >= sd1;            // stable argsort(-depth)
      const float ra = keep ? r0 : r1;
      const float rb = keep ? r1 : r0;
      rank_c += fmaxf(ra - rb + 1e-4f, 0.f);
      cont_c += fmaxf(fabsf(r0 - q0) - 1e-4f, 0.f)
              + fmaxf(fabsf(r1 - q1) - 1e-4f, 0.f);
      cnt_c  += 1.f;
    }
  }

  // ------- block reduction: wave shuffles -> LDS -> 3 atomics ---------------
#pragma unroll
  for (int off = 32; off > 0; off >>= 1) {
    rank_c += __shfl_down(rank_c, off);
    cont_c += __shfl_down(cont_c, off);
    cnt_c  += __shfl_down(cnt_c, off);
  }
  if (lane == 0) {
    partial[wave * 3 + 0] = rank_c;
    partial[wave * 3 + 1] = cont_c;
    partial[wave * 3 + 2] = cnt_c;
  }
  __syncthreads();
  if (tid < 3) {
    const float s = partial[tid] + partial[3 + tid] +
                    partial[6 + tid] + partial[9 + tid];
    atomicAdd(acc + tid, s);
  }
}

__global__ void gs_finalize(const float* __restrict__ acc, float* __restrict__ out)
{
  const float denom = fmaxf(acc[2], 1.0f);
  out[0] = 0.2f  * (acc[0] / denom);                // WEIGHT * rank_mean
  out[1] = 0.02f * (acc[1] / (denom * 2.0f));       // WEIGHT*CONT_W * cont_mean
}

extern "C" void kernel_launch(void* const* d_in, const int* in_sizes, int n_in,
                              void* d_out, int out_size, void* d_ws, size_t ws_size,
                              hipStream_t stream)
{
  (void)in_sizes; (void)n_in; (void)out_size;
  const float* tgt   = (const float*)d_in[0];
  const float* rnd   = (const float*)d_in[1];
  const int*   vmask = (const int*)d_in[2];
  float* out = (float*)d_out;

  // ws layout: [acc 3f + pad = 16B][vbits bit table 259200B]
  float* acc  = (float*)d_ws;
  ull*   vbits = (ull*)((char*)d_ws + 16);
  const size_t need = 16 + (size_t)(N_PIX / 64) * 8;

  Keys K;
  compute_keys(K);

  hipMemsetAsync(acc, 0, 16, stream);

  const bool use_bits = (ws_size >= need);
  if (use_bits)
    gs_bitpack<<<N_PIX / 256, 256, 0, stream>>>(vmask, vbits);

  gs_fused<<<MAIN_BLKS, 256, 0, stream>>>(tgt, rnd, vmask,
                                          use_bits ? vbits : nullptr, acc, K);
  gs_finalize<<<1, 1, 0, stream>>>(acc, out);
}

// Round 14
// 62.993 us; speedup vs baseline: 1.3564x; 1.0426x over previous
//
#include <hip/hip_runtime.h>
#include <stdint.h>

// ---------------------------------------------------------------------------
// GSDepthRankingLoss on MI355X — R14 = R3 champion (fp32 crops, 60.4us,
// absmax 0) + occupancy attack: 128-thread blocks, 256 samples/block ->
// 2025 blocks (~16 waves/CU, 2x R3). Phase B dense (1 crop/thread). Center
// depth taken from loaded crop row 3 (one less gather per crop).
// JAX threefry (partitionable) verified bit-exact R0-R13.
// ---------------------------------------------------------------------------

#define IMG_W 1920
#define IMG_H 1080
#define N_PIX (IMG_W * IMG_H)
#define N_SAMP 518400          // int(1920*1080*0.25) == 2025 * 256
#define MAIN_BLKS 2025
#define PAD_VAL (-1000000.0f)

typedef unsigned long long ull;

struct Keys { uint32_t k[5][2][2]; };  // [randint id][k1|k2][key word]

// Threefry-2x32, 20 rounds (Random123 / JAX-compatible).
static __host__ __device__ inline void tf2x32(uint32_t k0, uint32_t k1,
                                              uint32_t x0, uint32_t x1,
                                              uint32_t& o0, uint32_t& o1)
{
  const uint32_t ks2 = k0 ^ k1 ^ 0x1BD11BDAu;
  x0 += k0; x1 += k1;
#define TFR(r) { x0 += x1; x1 = (x1 << (r)) | (x1 >> (32 - (r))); x1 ^= x0; }
  TFR(13) TFR(15) TFR(26) TFR(6)
  x0 += k1;  x1 += ks2 + 1u;
  TFR(17) TFR(29) TFR(16) TFR(24)
  x0 += ks2; x1 += k0 + 2u;
  TFR(13) TFR(15) TFR(26) TFR(6)
  x0 += k0;  x1 += k1 + 3u;
  TFR(17) TFR(29) TFR(16) TFR(24)
  x0 += k1;  x1 += ks2 + 4u;
  TFR(13) TFR(15) TFR(26) TFR(6)
  x0 += ks2; x1 += k0 + 5u;
#undef TFR
  o0 = x0; o1 = x1;
}

__device__ __forceinline__ uint32_t jrbits(const uint32_t kk[2], uint32_t f)
{
  uint32_t a, b;
  tf2x32(kk[0], kk[1], 0u, f, a, b);   // partitionable: counts = (0, f)
  return a ^ b;                        // 32-bit fold
}

__device__ __forceinline__ uint32_t jrandint(const Keys& K, int r, uint32_t f,
                                             uint32_t span)
{
  const uint32_t hi = jrbits(K.k[r][0], f);
  const uint32_t lo = jrbits(K.k[r][1], f);
  uint32_t m = 65536u % span;
  m = (m * m) % span;
  return ((hi % span) * m + (lo % span)) % span;
}

static void compute_keys(Keys& K)
{
  uint32_t ks[5][2];
  for (uint32_t t = 0; t < 5; t++) {
    uint32_t a, b; tf2x32(0u, 42u, 0u, t, a, b);   // split of key(42)
    ks[t][0] = a; ks[t][1] = b;
  }
  for (int r = 0; r < 5; r++) {                    // randint's internal _split
    uint32_t a, b;
    tf2x32(ks[r][0], ks[r][1], 0u, 0u, a, b); K.k[r][0][0] = a; K.k[r][0][1] = b;
    tf2x32(ks[r][0], ks[r][1], 0u, 1u, a, b); K.k[r][1][0] = a; K.k[r][1][1] = b;
  }
}

// valid test: bit table if available (L2-resident), else raw int mask
__device__ __forceinline__ bool validat(const ull* __restrict__ vb,
                                        const int* __restrict__ vm, uint32_t idx)
{
  if (vb) return ((vb[idx >> 6] >> (idx & 63u)) & 1ull) != 0ull;
  return vm[idx] != 0;
}

// ---------------- K1: bitpack valid mask (2073600 ints -> 259KB) ------------
__global__ __launch_bounds__(256) void gs_bitpack(
    const int* __restrict__ vmask,
    ull* __restrict__ vbits)
{
  const uint32_t gid = blockIdx.x * 256u + threadIdx.x;   // 8100*256 == N_PIX
  const ull ball = __ballot(vmask[gid] != 0);
  if ((threadIdx.x & 63u) == 0) vbits[gid >> 6] = ball;
}

// nbr-th nearest neighbour (by |depth-sd|, stable position ties) of the 7x7
// crop at (sy,sx). Compiler-scheduled memcpy row loads (the proven-best
// variant). Center depth comes from the loaded rows (v[3][3]) via sd_out.
__device__ __forceinline__ int crop_neighbor32(const float* __restrict__ tgt,
                                               int sy, int sx,
                                               float& sd_out, uint32_t nbr)
{
  float v[7][8];
  const bool interior = (sy >= 3) && (sy <= IMG_H - 4) &&
                        (sx >= 3) && (sx <= IMG_W - 5);
  if (interior) {
    const float* p = tgt + (sy - 3) * IMG_W + (sx - 3);
#pragma unroll
    for (int r = 0; r < 7; r++)
      __builtin_memcpy(&v[r][0], p + r * IMG_W, 32);   // 2x dwordx4
  } else {
    // rare edge path (~1e-4): guarded scalar loads, PAD semantics
#pragma unroll
    for (int r = 0; r < 7; r++) {
      const int yy = sy - 3 + r;
      const bool rok = (yy >= 0) && (yy < IMG_H);
#pragma unroll
      for (int c = 0; c < 8; c++) {
        const int xx = sx - 3 + c;
        const bool okc = rok && (c < 7) && (xx >= 0) && (xx < IMG_W);
        v[r][c] = okc ? tgt[yy * IMG_W + xx] : PAD_VAL;
      }
    }
  }
  const float sd = v[3][3];          // center (sy,sx) — always in-bounds
  sd_out = sd;

  // 15 smallest of 49 keys: (|v-sd|bits & ~63) | pos; stable ties by pos.
  uint32_t arr[15];
#pragma unroll
  for (int t = 0; t < 15; t++) arr[t] = 0xFFFFFFFFu;

#pragma unroll
  for (int r = 0; r < 7; r++) {
#pragma unroll
    for (int c = 0; c < 7; c++) {
      const int q = r * 7 + c;
      uint32_t key = (__float_as_uint(v[r][c] - sd) & 0x7FFFFFC0u) | (uint32_t)q;
      const int depth = (q + 1 < 15) ? (q + 1) : 15;   // triangular insert
#pragma unroll
      for (int t = 0; t < 15; t++) {
        if (t < depth) {
          const uint32_t lo = min(key, arr[t]);
          const uint32_t hi = max(key, arr[t]);
          arr[t] = lo; key = hi;
        }
      }
    }
  }

  uint32_t relkey = 0;
#pragma unroll
  for (int t = 1; t < 15; t++)
    if ((uint32_t)t == nbr) relkey = arr[t];
  const uint32_t rel = relkey & 63u;
  return (sy - 3 + (int)(rel / 7u)) * IMG_W + (sx - 3 + (int)(rel % 7u));
}

// ---------------- K2: fused main, 128 threads, 256 samples/block ------------
// ent (64b): [ui:20 @44][sy0:11 @33][sx0:11 @22][sy1:11 @11][sx1:11 @0]
__global__ __launch_bounds__(128, 4) void gs_fused(
    const float* __restrict__ tgt,
    const float* __restrict__ rnd,
    const int*   __restrict__ vmask,
    const ull*   __restrict__ vbits,   // may be nullptr
    float* __restrict__ acc,
    Keys K)
{
  __shared__ ull      ent[256];
  __shared__ float    res_sd[512];
  __shared__ int      res_ni[512];
  __shared__ uint32_t scnt[4];         // [h][wave]
  __shared__ float    partial[6];

  const uint32_t tid  = threadIdx.x;
  const uint32_t lane = tid & 63u;
  const uint32_t wave = tid >> 6;      // 0..1

  // ------- phase A: PRNG + sample mask, 2 samples/thread, LDS compaction ----
  ull  eb[2];
  ull  bal[2];
  bool ok[2];
#pragma unroll
  for (int h = 0; h < 2; h++) {
    const uint32_t ui = blockIdx.x * 256u + (uint32_t)h * 128u + tid;  // exact
    const uint32_t syb = jrandint(K, 0, ui, 840u);    // H - 240
    const uint32_t sxb = jrandint(K, 1, ui, 1680u);   // W - 240
    const uint32_t oy0 = jrandint(K, 2, 2u * ui,      240u);
    const uint32_t oy1 = jrandint(K, 2, 2u * ui + 1u, 240u);
    const uint32_t ox0 = jrandint(K, 3, 2u * ui,      240u);
    const uint32_t ox1 = jrandint(K, 3, 2u * ui + 1u, 240u);
    const uint32_t sy0 = syb + oy0, sy1 = syb + oy1;
    const uint32_t sx0 = sxb + ox0, sx1 = sxb + ox1;
    ok[h] = validat(vbits, vmask, sy0 * IMG_W + sx0) &&
            validat(vbits, vmask, sy1 * IMG_W + sx1);
    eb[h] = ((ull)ui << 44) |
            ((ull)sy0 << 33) | ((ull)sx0 << 22) |
            ((ull)sy1 << 11) |  (ull)sx1;
    bal[h] = __ballot(ok[h]);
    if (lane == 0) scnt[(uint32_t)h * 2u + wave] = (uint32_t)__popcll(bal[h]);
  }
  __syncthreads();

  uint32_t run = 0, baseh[2];
#pragma unroll
  for (uint32_t h = 0; h < 2; h++) {
    baseh[h] = run + ((wave == 1u) ? scnt[h * 2u] : 0u);
    run += scnt[h * 2u] + scnt[h * 2u + 1u];
  }
  const uint32_t nsurv = run;

#pragma unroll
  for (int h = 0; h < 2; h++)
    if (ok[h])
      ent[baseh[h] + (uint32_t)__popcll(bal[h] & ((1ull << lane) - 1ull))] = eb[h];
  __syncthreads();

  // ------- phase B: one 7x7 crop per thread (dense, ~2*nsurv ~= 128) --------
  for (uint32_t t = tid; t < 2u * nsurv; t += 128u) {
    const ull ee = ent[t >> 1];
    const int jj = (int)(t & 1u);
    const uint32_t eui = (uint32_t)(ee >> 44);
    const int sy = jj ? (int)((ee >> 11) & 2047u) : (int)((ee >> 33) & 2047u);
    const int sx = jj ? (int)( ee        & 2047u) : (int)((ee >> 22) & 2047u);
    const uint32_t nbr = 1u + jrandint(K, 4, 2u * eui + (uint32_t)jj, 14u);
    float sd;
    const int nidx = crop_neighbor32(tgt, sy, sx, sd, nbr);
    res_sd[t] = sd;
    res_ni[t] = validat(vbits, vmask, (uint32_t)nidx) ? nidx : -1;
  }
  __syncthreads();

  // ------- phase C: pair combine + loss --------------------------------------
  float rank_c = 0.f, cont_c = 0.f, cnt_c = 0.f;
  for (uint32_t sI = tid; sI < nsurv; sI += 128u) {
    const int n0 = res_ni[2u * sI], n1 = res_ni[2u * sI + 1u];
    if ((n0 >= 0) && (n1 >= 0)) {
      const ull ee = ent[sI];
      const int esy0 = (int)((ee >> 33) & 2047u), esx0 = (int)((ee >> 22) & 2047u);
      const int esy1 = (int)((ee >> 11) & 2047u), esx1 = (int)( ee        & 2047u);
      const float r0 = rnd[esy0 * IMG_W + esx0];
      const float r1 = rnd[esy1 * IMG_W + esx1];
      const float q0 = rnd[n0], q1 = rnd[n1];
      const float sd0 = res_sd[2u * sI], sd1 = res_sd[2u * sI + 1u];
      const bool keep = sd0 >= sd1;            // stable argsort(-depth)
      const float ra = keep ? r0 : r1;
      const float rb = keep ? r1 : r0;
      rank_c += fmaxf(ra - rb + 1e-4f, 0.f);
      cont_c += fmaxf(fabsf(r0 - q0) - 1e-4f, 0.f)
              + fmaxf(fabsf(r1 - q1) - 1e-4f, 0.f);
      cnt_c  += 1.f;
    }
  }

  // ------- block reduction: wave shuffles -> LDS -> 3 atomics ---------------
#pragma unroll
  for (int off = 32; off > 0; off >>= 1) {
    rank_c += __shfl_down(rank_c, off);
    cont_c += __shfl_down(cont_c, off);
    cnt_c  += __shfl_down(cnt_c, off);
  }
  if (lane == 0) {
    partial[wave * 3 + 0] = rank_c;
    partial[wave * 3 + 1] = cont_c;
    partial[wave * 3 + 2] = cnt_c;
  }
  __syncthreads();
  if (tid < 3) {
    const float s = partial[tid] + partial[3 + tid];
    atomicAdd(acc + tid, s);
  }
}

__global__ void gs_finalize(const float* __restrict__ acc, float* __restrict__ out)
{
  const float denom = fmaxf(acc[2], 1.0f);
  out[0] = 0.2f  * (acc[0] / denom);                // WEIGHT * rank_mean
  out[1] = 0.02f * (acc[1] / (denom * 2.0f));       // WEIGHT*CONT_W * cont_mean
}

extern "C" void kernel_launch(void* const* d_in, const int* in_sizes, int n_in,
                              void* d_out, int out_size, void* d_ws, size_t ws_size,
                              hipStream_t stream)
{
  (void)in_sizes; (void)n_in; (void)out_size;
  const float* tgt   = (const float*)d_in[0];
  const float* rnd   = (const float*)d_in[1];
  const int*   vmask = (const int*)d_in[2];
  float* out = (float*)d_out;

  // ws layout: [acc 3f + pad = 16B][vbits bit table 259200B]
  float* acc  = (float*)d_ws;
  ull*   vbits = (ull*)((char*)d_ws + 16);
  const size_t need = 16 + (size_t)(N_PIX / 64) * 8;

  Keys K;
  compute_keys(K);

  hipMemsetAsync(acc, 0, 16, stream);

  const bool use_bits = (ws_size >= need);
  if (use_bits)
    gs_bitpack<<<N_PIX / 256, 256, 0, stream>>>(vmask, vbits);

  gs_fused<<<MAIN_BLKS, 128, 0, stream>>>(tgt, rnd, vmask,
                                          use_bits ? vbits : nullptr, acc, K);
  gs_finalize<<<1, 1, 0, stream>>>(acc, out);
}